// Round 7
// baseline (414.861 us; speedup 1.0000x reference)
//
#include <hip/hip_runtime.h>
#include <hip/hip_bf16.h>
#include <math.h>

#define BATCH 4
#define HEADS 16
#define SEQ   2048
#define DIM   128
#define BHN   (BATCH*HEADS)

#define BQ 128   // q rows per block (4 waves x WQ=32)
#define WQ 32    // q rows per wave (2 MFMA M-blocks: amortizes K/V LDS reads 2x vs WQ=16)
#define KT 32    // k rows per stage/compute tile
#define NXB (SEQ/BQ)   // 16 q-blocks per bh

typedef short bf16x8 __attribute__((ext_vector_type(8)));
typedef float f32x4  __attribute__((ext_vector_type(4)));

static __device__ __forceinline__ unsigned short f2bf(float f) {
    union { float f; unsigned u; } x; x.f = f;
    unsigned r = x.u + 0x7FFF + ((x.u >> 16) & 1);  // RNE
    return (unsigned short)(r >> 16);
}

// async 16B global -> LDS (no data VGPRs; LDS dest = wave-uniform base + lane*16)
static __device__ __forceinline__ void async_cp16(const unsigned short* g, unsigned short* l) {
    __builtin_amdgcn_global_load_lds(
        (const __attribute__((address_space(1))) unsigned int*)g,
        (__attribute__((address_space(3))) unsigned int*)l,
        16, 0, 0);
}

// ------------- fused fp32->bf16: K row-major, V^T via in-register transpose -------------
// (R6-verified LDS-free version; pure streaming, both sides >=128B contiguous/16 lanes)
__global__ __launch_bounds__(256) void cvt_kv(
    const float* __restrict__ k, const float* __restrict__ v,
    unsigned short* __restrict__ kb, unsigned short* __restrict__ vt) {
    const int bh = blockIdx.y;
    const int s0 = blockIdx.x * 64;
    const int t  = threadIdx.x;
    const long rbase = ((long)bh * SEQ + s0) * DIM;

    // K: 64 rows x 128 = 8192 elems, 32/thread, packed converts
    #pragma unroll
    for (int u = 0; u < 2; ++u) {
        long e = rbase + (long)(t + u * 256) * 16;
        const float* src = k + e;
        unsigned short* dst = kb + e;
        #pragma unroll
        for (int h = 0; h < 2; ++h) {
            float4 a0 = *(const float4*)(src + h * 8);
            float4 a1 = *(const float4*)(src + h * 8 + 4);
            union { uint4 q; __hip_bfloat162 b[4]; } p;
            p.b[0] = __float22bfloat162_rn(float2{a0.x, a0.y});
            p.b[1] = __float22bfloat162_rn(float2{a0.z, a0.w});
            p.b[2] = __float22bfloat162_rn(float2{a1.x, a1.y});
            p.b[3] = __float22bfloat162_rn(float2{a1.z, a1.w});
            *(uint4*)(dst + h * 8) = p.q;
        }
    }
    // V: rg = t&15 (s-rows rg*4..+3), dg = t>>4 (d = dg*8..+7); 4x8 micro-transpose in regs
    {
        const int rg = t & 15;
        const int dg = t >> 4;
        const float* src = v + rbase + (long)(rg * 4) * DIM + dg * 8;
        float a[4][8];
        #pragma unroll
        for (int rr = 0; rr < 4; ++rr) {
            float4 x = *(const float4*)(src + rr * DIM);
            float4 y = *(const float4*)(src + rr * DIM + 4);
            a[rr][0]=x.x; a[rr][1]=x.y; a[rr][2]=x.z; a[rr][3]=x.w;
            a[rr][4]=y.x; a[rr][5]=y.y; a[rr][6]=y.z; a[rr][7]=y.w;
        }
        unsigned short* dstb = vt + ((long)bh * DIM + dg * 8) * SEQ + s0 + rg * 4;
        #pragma unroll
        for (int dd = 0; dd < 8; ++dd) {
            union { uint2 u; __hip_bfloat162 b[2]; } p;
            p.b[0] = __float22bfloat162_rn(float2{a[0][dd], a[1][dd]});
            p.b[1] = __float22bfloat162_rn(float2{a[2][dd], a[3][dd]});
            *(uint2*)(dstb + (long)dd * SEQ) = p.u;
        }
    }
}

// ---------------- flash attention ----------------
// R7: WQ=32 halves LDS-pipe + VALU demand per unit work (K/V tile reads amortized
// over 32 q-rows); (256,3) keeps 12 waves/CU (the residency R6 actually achieved).
// Reg footprint ~164 (VGPR ~100 + 64 acc) vs 512/3=170 cap.
// TRIPWIRE: WRITE_SIZE >> 65 MB = spill (R1 lesson) -> revert to (256,2).
__global__ __launch_bounds__(256, 3) void attn_fwd(
    const float* __restrict__ qg,
    const unsigned short* __restrict__ kb,
    const unsigned short* __restrict__ vtg,
    float* __restrict__ out) {

    __shared__ unsigned short Kt[2][KT][DIM];       // 2 x 32 x 128 (8 KB each)
    __shared__ unsigned short Vt[2][DIM][KT];       // 2 x 128 x 32 (8 KB each)
    __shared__ unsigned short Pl[4][2][16][KT + 8]; // per-wave, per-mb P tile (10 KB)

    const int tid  = threadIdx.x;
    const int w    = tid >> 6;
    const int lane = tid & 63;
    const int quad = lane >> 4;
    const int ql   = lane & 15;

    // Work-balance + locality swizzle, 1024 blocks (R2-verified):
    // bh fixed along a CU's co-residents; xb residue classes sum to 30 each.
    const int flat = blockIdx.x;
    const int xcd  = flat & 7;
    const int slot = flat >> 3;
    const int bh   = (xcd << 3) | (slot & 7);
    const int shi  = slot >> 3;
    // xbmap = {15,14,13,12, 0,1,2,3, 8,9,10,11, 7,6,5,4}
    const int xb   = (shi < 4) ? (15 - shi)
                   : (shi < 8) ? (shi - 4)
                   : (shi < 12) ? shi
                   : (19 - shi);
    const int qb0 = xb * BQ;
    const int qw0 = qb0 + w * WQ;

    const long base = (long)bh * SEQ * DIM;
    // exp2 domain: log2(e) folded into Q scale; p = exp2(s' - m') via v_exp_f32.
    const float scale = 0.08838834764831845f * 1.4426950408889634f;

    // ---- Q fragments (B-operand for Sc = K*Q^T), pre-scaled; two 16-row M-blocks ----
    bf16x8 qf[2][4];
    #pragma unroll
    for (int mb = 0; mb < 2; ++mb) {
        const float* qr = qg + base + (long)(qw0 + mb * 16 + ql) * DIM;
        #pragma unroll
        for (int c = 0; c < 4; ++c) {
            const float* p = qr + c * 32 + quad * 8;
            float4 x = *(const float4*)(p);
            float4 y = *(const float4*)(p + 4);
            union { bf16x8 v; unsigned short s[8]; } u;
            u.s[0]=f2bf(x.x*scale); u.s[1]=f2bf(x.y*scale);
            u.s[2]=f2bf(x.z*scale); u.s[3]=f2bf(x.w*scale);
            u.s[4]=f2bf(y.x*scale); u.s[5]=f2bf(y.y*scale);
            u.s[6]=f2bf(y.z*scale); u.s[7]=f2bf(y.w*scale);
            qf[mb][c] = u.v;
        }
    }

    f32x4 acc[2][8];
    #pragma unroll
    for (int mb = 0; mb < 2; ++mb)
        #pragma unroll
        for (int n = 0; n < 8; ++n)
            acc[mb][n] = (f32x4){0.f, 0.f, 0.f, 0.f};

    float m_[2] = {-INFINITY, -INFINITY};
    float l_[2] = {0.f, 0.f};

    // ---- staging: uniform tile base + loop-invariant lane offsets (R6 diet) ----
    int koff[2], voff[2];
    #pragma unroll
    for (int i = 0; i < 2; ++i) {
        const int idx = tid + i * 256;
        const int r   = idx >> 4;
        const int chg = (idx & 15) ^ (r & 15);       // K chunk swizzle
        koff[i] = r * DIM + chg * 8;
        const int d   = idx >> 2;
        const int cvg = (idx & 3) ^ ((d >> 1) & 3);  // V chunk swizzle
        voff[i] = d * SEQ + cvg * 8;
    }
    const int ldso = ((tid >> 6) * 64) * 8;          // wave-uniform LDS chunk offset
    const unsigned short* kbb = kb + base;
    const unsigned short* vbb = vtg + base;

    auto stage = [&](int buf, int k0s) {
        const unsigned short* ku = kbb + k0s * DIM;  // wave-uniform (scalar k0s)
        const unsigned short* vu = vbb + k0s;
        #pragma unroll
        for (int i = 0; i < 2; ++i) {
            async_cp16(ku + koff[i], &Kt[buf][0][0] + ldso + i * 2048);
            async_cp16(vu + voff[i], &Vt[buf][0][0] + ldso + i * 2048);
        }
    };

    // ---- hoisted LDS fragment base pointers (buf/mb fold to immediates) ----
    const unsigned short* kfb[4];
    #pragma unroll
    for (int c = 0; c < 4; ++c)
        kfb[c] = &Kt[0][ql][((c * 4 + quad) ^ ql) * 8];
    const unsigned short* vfb = &Vt[0][0][0] + ql * KT + (quad ^ ((ql >> 1) & 3)) * 8;
    unsigned short*       pwb = &Pl[0][0][0][0] + w * (2 * 16 * (KT + 8)) + ql * (KT + 8);
    const unsigned short* prb = pwb + quad * 8;
    const int PMB = 16 * (KT + 8);   // mb stride in Pl (shorts)

    // one tile's compute; buf is a LITERAL at both call sites
    auto body = [&](const int buf, const int k0) {
        if (k0 >= qw0 + WQ) return;          // inactive wave: straight to next barrier
        const int kbo = buf * (KT * DIM);    // folds to ds offset immediates
        const int vbo = buf * (DIM * KT);

        // ---- Sc = K * Q^T  (rows=k, cols=q) ----
        f32x4 sacc[2][2];
        #pragma unroll
        for (int mb = 0; mb < 2; ++mb)
            #pragma unroll
            for (int kk = 0; kk < 2; ++kk)
                sacc[mb][kk] = (f32x4){0.f, 0.f, 0.f, 0.f};
        __builtin_amdgcn_s_setprio(1);
        #pragma unroll
        for (int c = 0; c < 4; ++c) {
            bf16x8 kf0 = *(const bf16x8*)(kfb[c] + kbo);
            bf16x8 kf1 = *(const bf16x8*)(kfb[c] + kbo + 16 * DIM);
            #pragma unroll
            for (int mb = 0; mb < 2; ++mb) {
                sacc[mb][0] = __builtin_amdgcn_mfma_f32_16x16x32_bf16(kf0, qf[mb][c], sacc[mb][0], 0, 0, 0);
                sacc[mb][1] = __builtin_amdgcn_mfma_f32_16x16x32_bf16(kf1, qf[mb][c], sacc[mb][1], 0, 0, 0);
            }
        }
        __builtin_amdgcn_s_setprio(0);

        // V fragments (swizzled) — issued before softmax so lgkm hides under VALU
        bf16x8 vf[8];
        #pragma unroll
        for (int n = 0; n < 8; ++n)
            vf[n] = *(const bf16x8*)(vfb + vbo + n * (16 * KT));

        // ---- softmax both mb, write both P tiles (defer-max THR=4, exp2 domain) ----
        float alpha_[2];
        bool  resc_[2];
        #pragma unroll
        for (int mb = 0; mb < 2; ++mb) {
            const int qrow   = qw0 + mb * 16 + ql;
            const bool needm = (k0 + KT - 1 > qw0 + mb * 16);  // wave-uniform
            float s[2][4];
            float tmax = -INFINITY;
            #pragma unroll
            for (int kk = 0; kk < 2; ++kk)
                #pragma unroll
                for (int r = 0; r < 4; ++r) {
                    float sv = sacc[mb][kk][r];
                    if (needm) {
                        int kg = k0 + kk * 16 + quad * 4 + r;
                        sv = (kg <= qrow) ? sv : -INFINITY;
                    }
                    s[kk][r] = sv;
                    tmax = fmaxf(tmax, sv);
                }
            tmax = fmaxf(tmax, __shfl_xor(tmax, 16));
            tmax = fmaxf(tmax, __shfl_xor(tmax, 32));

            // T13 defer-max: P bounded by 2^4=16 (bf16-safe; THR=8 hurt absmax in R3)
            const bool skip = __all(tmax <= m_[mb] + 4.0f);
            const float mnew = skip ? m_[mb] : fmaxf(m_[mb], tmax);

            float rsum = 0.f;
            #pragma unroll
            for (int kk = 0; kk < 2; ++kk) {
                float p0 = __builtin_amdgcn_exp2f(s[kk][0] - mnew);
                float p1 = __builtin_amdgcn_exp2f(s[kk][1] - mnew);
                float p2 = __builtin_amdgcn_exp2f(s[kk][2] - mnew);
                float p3 = __builtin_amdgcn_exp2f(s[kk][3] - mnew);
                rsum += (p0 + p1) + (p2 + p3);
                union { uint2 u; __hip_bfloat162 h[2]; } pu;   // v_cvt_pk_bf16_f32
                pu.h[0] = __float22bfloat162_rn(float2{p0, p1});
                pu.h[1] = __float22bfloat162_rn(float2{p2, p3});
                *(uint2*)(pwb + mb * PMB + kk * 16 + quad * 4) = pu.u;
            }
            rsum += __shfl_xor(rsum, 16);
            rsum += __shfl_xor(rsum, 32);

            if (skip) {
                l_[mb] += rsum;
                alpha_[mb] = 1.f; resc_[mb] = false;
            } else {
                const float al = __builtin_amdgcn_exp2f(m_[mb] - mnew);
                l_[mb] = l_[mb] * al + rsum;
                m_[mb] = mnew;
                alpha_[mb] = al; resc_[mb] = true;
            }
        }

        // ---- read both pf (mb=1 softmax hides mb=0's ds_write->read lgkm) ----
        bf16x8 pf0 = *(const bf16x8*)(prb);
        bf16x8 pf1 = *(const bf16x8*)(prb + PMB);

        #pragma unroll
        for (int mb = 0; mb < 2; ++mb) {
            if (resc_[mb]) {   // wave-uniform; rare after warm-up
                #pragma unroll
                for (int r = 0; r < 4; ++r) {
                    float ar = __shfl(alpha_[mb], quad * 4 + r);
                    #pragma unroll
                    for (int n = 0; n < 8; ++n) acc[mb][n][r] *= ar;
                }
            }
            const bf16x8 pf = mb ? pf1 : pf0;
            __builtin_amdgcn_s_setprio(1);
            #pragma unroll
            for (int n = 0; n < 8; ++n)
                acc[mb][n] = __builtin_amdgcn_mfma_f32_16x16x32_bf16(pf, vf[n], acc[mb][n], 0, 0, 0);
            __builtin_amdgcn_s_setprio(0);
        }
    };

    const int ntile = 4 * xb + 4;   // always even

    stage(0, 0);

    for (int tt = 0; tt < ntile; tt += 2) {
        __syncthreads();   // tile tt resident; prior readers of buf0 done
        stage(1, (tt + 1) * KT);
        body(0, tt * KT);

        __syncthreads();   // tile tt+1 resident; prior readers of buf1 done
        if (tt + 2 < ntile) stage(0, (tt + 2) * KT);
        body(1, (tt + 1) * KT);
    }

    // ---- epilogue: O / l ----
    #pragma unroll
    for (int mb = 0; mb < 2; ++mb) {
        #pragma unroll
        for (int r = 0; r < 4; ++r) {
            float lr = __shfl(l_[mb], quad * 4 + r);
            float il = 1.0f / lr;
            long orow = base + (long)(qw0 + mb * 16 + quad * 4 + r) * DIM;
            #pragma unroll
            for (int n = 0; n < 8; ++n)
                out[orow + n * 16 + ql] = acc[mb][n][r] * il;
        }
    }
}

extern "C" void kernel_launch(void* const* d_in, const int* in_sizes, int n_in,
                              void* d_out, int out_size, void* d_ws, size_t ws_size,
                              hipStream_t stream) {
    const float* k = (const float*)d_in[0];
    const float* q = (const float*)d_in[1];
    const float* v = (const float*)d_in[2];
    float* o = (float*)d_out;

    unsigned short* kb = (unsigned short*)d_ws;
    unsigned short* vt = kb + (size_t)BHN * SEQ * DIM;

    cvt_kv<<<dim3(SEQ / 64, BHN), dim3(256), 0, stream>>>(k, v, kb, vt);

    attn_fwd<<<dim3(NXB * BHN), dim3(256), 0, stream>>>(q, kb, vt, o);
}